// Round 8
// baseline (243.005 us; speedup 1.0000x reference)
//
#include <hip/hip_runtime.h>
#include <math.h>

#define NPOS 13824   // 24*24*24
#define CDIM 64
#define BTCH 2
#define LOG2E 1.4426950408889634f
#define QSCALE (0.125f * LOG2E)

__device__ __forceinline__ unsigned int f2bf1(float f) {   // RNE float->bf16
  unsigned int u = __float_as_uint(f);
  return (u + 0x7FFFu + ((u >> 16) & 1u)) >> 16;
}

// ---------------------------------------------------------------------------
// Kernel 1: projections. Outputs (B,N,C): KVp = bf16 K|V packed (bias incl.),
// QGX = {bf16 q(prescaled)|gateX, fp32 x} 8 B records. Zeroes pool.
// ---------------------------------------------------------------------------
__global__ __launch_bounds__(256) void qkvg_kernel(
    const float* __restrict__ x,
    const float* __restrict__ Wq, const float* __restrict__ bq,
    const float* __restrict__ Wk, const float* __restrict__ bk,
    const float* __restrict__ Wv, const float* __restrict__ bv,
    const float* __restrict__ Wg,
    unsigned int* __restrict__ KVp, float* __restrict__ QGX,
    float* __restrict__ pool)
{
  __shared__ __align__(16) float wqt[64*68];
  __shared__ __align__(16) float wkt[64*68];
  __shared__ __align__(16) float wvt[64*68];
  __shared__ __align__(16) float wgt[64*68];
  const int t  = threadIdx.x;
  const int bi = blockIdx.x;
  const int b  = bi / 216;
  const int n0 = (bi - b*216) * 64;
  if (bi == 0 && t < 128) pool[t] = 0.0f;

  #pragma unroll
  for (int k = 0; k < 16; ++k) {
    int idx = t + k*256;                 // 0..4095
    int lo = idx & 63, hi = idx >> 6;
    wqt[lo*68 + hi] = Wq[idx] * QSCALE;  // [c_in][c_out], Q pre-scaled
    wkt[lo*68 + hi] = Wk[idx];
    wvt[lo*68 + hi] = Wv[idx];
    wgt[lo*68 + hi] = Wg[hi*128 + lo];   // first 64 columns of Wg
  }
  __syncthreads();

  const int c0  = (t & 15) * 4;          // 4 output channels
  const int nn0 = (t >> 4) * 4;          // 4 positions
  const float* xbase = x + (size_t)(b*64)*NPOS + n0 + nn0;
  float aq[4][4] = {}; float ak[4][4] = {}; float av[4][4] = {}; float ag[4][4] = {};
  #pragma unroll 4
  for (int cp = 0; cp < 64; ++cp) {
    const float4 xv4 = *(const float4*)(xbase + (size_t)cp*NPOS);
    const float4 q4  = *(const float4*)&wqt[cp*68 + c0];
    const float4 k4  = *(const float4*)&wkt[cp*68 + c0];
    const float4 v4  = *(const float4*)&wvt[cp*68 + c0];
    const float4 g4  = *(const float4*)&wgt[cp*68 + c0];
    const float xa[4] = {xv4.x, xv4.y, xv4.z, xv4.w};
    const float qa[4] = {q4.x, q4.y, q4.z, q4.w};
    const float ka[4] = {k4.x, k4.y, k4.z, k4.w};
    const float va[4] = {v4.x, v4.y, v4.z, v4.w};
    const float ga[4] = {g4.x, g4.y, g4.z, g4.w};
    #pragma unroll
    for (int ci = 0; ci < 4; ++ci)
      #pragma unroll
      for (int ni = 0; ni < 4; ++ni) {
        aq[ci][ni] = fmaf(qa[ci], xa[ni], aq[ci][ni]);
        ak[ci][ni] = fmaf(ka[ci], xa[ni], ak[ci][ni]);
        av[ci][ni] = fmaf(va[ci], xa[ni], av[ci][ni]);
        ag[ci][ni] = fmaf(ga[ci], xa[ni], ag[ci][ni]);
      }
  }
  // re-read x tile rows c0..c0+3 (L1-hot) for the x field of QGX
  float4 xr[4];
  #pragma unroll
  for (int e = 0; e < 4; ++e)
    xr[e] = *(const float4*)(x + (size_t)(b*64 + c0 + e)*NPOS + n0 + nn0);
  const float xre[4][4] = {{xr[0].x,xr[0].y,xr[0].z,xr[0].w},
                           {xr[1].x,xr[1].y,xr[1].z,xr[1].w},
                           {xr[2].x,xr[2].y,xr[2].z,xr[2].w},
                           {xr[3].x,xr[3].y,xr[3].z,xr[3].w}};
  const float4 bq4 = *(const float4*)&bq[c0];
  const float4 bk4 = *(const float4*)&bk[c0];
  const float4 bv4 = *(const float4*)&bv[c0];
  const float bqa[4] = {bq4.x, bq4.y, bq4.z, bq4.w};
  const float bka[4] = {bk4.x, bk4.y, bk4.z, bk4.w};
  const float bva[4] = {bv4.x, bv4.y, bv4.z, bv4.w};
  #pragma unroll
  for (int ni = 0; ni < 4; ++ni) {
    const int p = b*NPOS + n0 + nn0 + ni;   // (N,C) layout: [p*64 + c]
    // packed bf16 K (hi) | V (lo), bias included
    uint4 kv;
    kv.x = (f2bf1(ak[0][ni]+bka[0]) << 16) | f2bf1(av[0][ni]+bva[0]);
    kv.y = (f2bf1(ak[1][ni]+bka[1]) << 16) | f2bf1(av[1][ni]+bva[1]);
    kv.z = (f2bf1(ak[2][ni]+bka[2]) << 16) | f2bf1(av[2][ni]+bva[2]);
    kv.w = (f2bf1(ak[3][ni]+bka[3]) << 16) | f2bf1(av[3][ni]+bva[3]);
    *(uint4*)&KVp[p*64 + c0] = kv;
    // QGX: {bf16 q|gateX, x} per (p,c)
    unsigned pk0 = (f2bf1(fmaf(bqa[0], QSCALE, aq[0][ni])) << 16) | f2bf1(ag[0][ni]);
    unsigned pk1 = (f2bf1(fmaf(bqa[1], QSCALE, aq[1][ni])) << 16) | f2bf1(ag[1][ni]);
    unsigned pk2 = (f2bf1(fmaf(bqa[2], QSCALE, aq[2][ni])) << 16) | f2bf1(ag[2][ni]);
    unsigned pk3 = (f2bf1(fmaf(bqa[3], QSCALE, aq[3][ni])) << 16) | f2bf1(ag[3][ni]);
    float4 o;
    o = make_float4(__uint_as_float(pk0), xre[0][ni], __uint_as_float(pk1), xre[1][ni]);
    *(float4*)&QGX[(size_t)(p*64 + c0)*2]     = o;
    o = make_float4(__uint_as_float(pk2), xre[2][ni], __uint_as_float(pk3), xre[3][ni]);
    *(float4*)&QGX[(size_t)(p*64 + c0)*2 + 4] = o;
  }
}

// ---------------------------------------------------------------------------
// Kernel 2: tiled attention. XCD-swizzled 3x3x3 tiles. Halo in LDS as
// [c][slot] rows (stride 129): all 27 neighbor reads are immediate offsets
// off one base -> ds_read2_b32 pairing. 4-position ILP per wave. Gate
// weights bf16-packed in VGPRs. Coalesced (N,C) result into OT.
// ---------------------------------------------------------------------------
__global__ __launch_bounds__(256, 4) void attn_kernel(
    float* __restrict__ OT,
    const unsigned int* __restrict__ KVp,
    const float* __restrict__ QGX,
    const float* __restrict__ bk, const float* __restrict__ bv,
    const float* __restrict__ memk, const float* __restrict__ memv,
    const float* __restrict__ Wg, const float* __restrict__ bg,
    float* __restrict__ pool)
{
  __shared__ __align__(16) unsigned int kvbuf[64*129]; // [c][slot0..124], pad 129
  __shared__ __align__(16) float als[4][256];
  const int t = threadIdx.x;
  const int c = t & 63;
  const int w = t >> 6;

  // stage Wg[:,64:] via padded-65 LDS transpose (overlay kvbuf), pack to bf16
  {
    float* wgt2 = (float*)kvbuf;
    #pragma unroll
    for (int k = 0; k < 16; ++k) {
      int u = t + k*256;
      int cp = u >> 6, j = u & 63;
      wgt2[j*65 + cp] = Wg[cp*128 + 64 + j];
    }
  }
  __syncthreads();
  unsigned int wg2p[32];                 // bf16 pair: lo=even j, hi=odd j
  {
    const float* wgt2 = (const float*)kvbuf;
    #pragma unroll
    for (int j2 = 0; j2 < 32; ++j2) {
      unsigned lo = f2bf1(wgt2[(2*j2)*65 + c]);
      unsigned hi = f2bf1(wgt2[(2*j2+1)*65 + c]);
      wg2p[j2] = lo | (hi << 16);
    }
  }
  float mk[5], mv[5];
  #pragma unroll
  for (int m = 0; m < 5; ++m) { mk[m] = memk[c*5 + m]; mv[m] = memv[c*5 + m]; }
  const float bg_c = bg[c];
  const unsigned bias_kv = (f2bf1(bk[c]) << 16) | f2bf1(bv[c]);
  __syncthreads();

  // XCD-aware swizzle: bi&7 = XCD; contiguous 128-tile slab per XCD for L2 reuse
  const int bi = (int)(blockIdx.x & 7) * 128 + (int)(blockIdx.x >> 3);
  const int b  = bi >> 9;                 // 512 tiles (8x8x8) per batch
  const int tb = bi & 511;
  const int h0 = (tb >> 6) * 3;
  const int d0 = ((tb >> 3) & 7) * 3;
  const int w0 = (tb & 7) * 3;
  const int bN = b * NPOS;

  // stage 5x5x5 halo into [c][slot] rows; pos wave-uniform, lane = channel
  for (int u = t; u < 8000; u += 256) {
    const int pos = u >> 6;               // 0..124, wave-uniform
    const int ph = pos / 25, pr = pos - ph*25;
    const int pd = pr / 5,  pw = pr - pd*5;
    const int hh = h0 - 1 + ph, dd = d0 - 1 + pd, ww = w0 - 1 + pw;
    const bool inb = ((unsigned)hh < 24u) && ((unsigned)dd < 24u) && ((unsigned)ww < 24u);
    unsigned kv = bias_kv;
    if (inb) kv = KVp[(size_t)(bN + hh*576 + dd*24 + ww)*64 + c];
    kvbuf[c*129 + pos] = kv;
  }
  __syncthreads();

  float pacc = 0.0f;
  #pragma unroll
  for (int half = 0; half < 2; ++half) {
    const int li0 = w + half*16;
    bool val[4]; int p[4]; const unsigned int* kvrow[4];
    float q2[4], gxl[4], xv[4];
    #pragma unroll
    for (int s = 0; s < 4; ++s) {
      int li = li0 + 4*s;
      val[s] = li < 27;
      if (!val[s]) li = li0;
      const int lh = li / 9, lr = li - lh*9;
      const int ld = lr / 3, lw = lr - ld*3;
      p[s]     = bN + (h0+lh)*576 + (d0+ld)*24 + (w0+lw);
      kvrow[s] = &kvbuf[c*129 + lh*25 + ld*5 + lw];
      const float2 gq = *(const float2*)&QGX[(size_t)(p[s]*64 + c)*2];
      const unsigned uq = __float_as_uint(gq.x);
      q2[s]  = __uint_as_float(uq & 0xFFFF0000u);   // pre-scaled q
      gxl[s] = __uint_as_float(uq << 16);           // gate x-half logit
      xv[s]  = gq.y;
    }

    // single-pass softmax (no max subtraction), 4 chains interleaved
    float s0[4] = {}, s1[4] = {}, o0[4] = {}, o1[4] = {};
    #pragma unroll
    for (int m = 0; m < 5; ++m)
      #pragma unroll
      for (int s = 0; s < 4; ++s) {
        const float pf = __builtin_amdgcn_exp2f(q2[s] * mk[m]);
        if (m & 1) { s1[s] += pf; o1[s] = fmaf(pf, mv[m], o1[s]); }
        else       { s0[s] += pf; o0[s] = fmaf(pf, mv[m], o0[s]); }
      }
    #pragma unroll
    for (int i = 0; i < 3; ++i)
      #pragma unroll
      for (int j = 0; j < 3; ++j)
        #pragma unroll
        for (int l = 0; l < 3; ++l) {
          const int s4  = i*9 + j*3 + l;
          const int off = i*25 + j*5 + l;     // immediate 0..62 -> ds_read2
          #pragma unroll
          for (int s = 0; s < 4; ++s) {
            const unsigned kv = kvrow[s][off];
            const float kf = __uint_as_float(kv & 0xFFFF0000u);
            const float vf = __uint_as_float(kv << 16);
            const float pf = __builtin_amdgcn_exp2f(q2[s] * kf);
            if (s4 & 1) { s1[s] += pf; o1[s] = fmaf(pf, vf, o1[s]); }
            else        { s0[s] += pf; o0[s] = fmaf(pf, vf, o0[s]); }
          }
        }
    float att[4];
    #pragma unroll
    for (int s = 0; s < 4; ++s) {
      att[s] = (o0[s] + o1[s]) * __builtin_amdgcn_rcpf(s0[s] + s1[s]);
      als[s][w*64 + c] = att[s];           // wave-local broadcast buffers
    }

    // gate matvec: 64-deep channel mix of att, weights in bf16-packed VGPRs
    float g0[4], g1[4] = {}, g2[4] = {}, g3[4] = {};
    #pragma unroll
    for (int s = 0; s < 4; ++s) g0[s] = gxl[s] + bg_c;
    #pragma unroll
    for (int j4 = 0; j4 < 16; ++j4) {
      const unsigned pk0 = wg2p[2*j4], pk1 = wg2p[2*j4+1];
      const float w0f = __uint_as_float(pk0 << 16);
      const float w1f = __uint_as_float(pk0 & 0xFFFF0000u);
      const float w2f = __uint_as_float(pk1 << 16);
      const float w3f = __uint_as_float(pk1 & 0xFFFF0000u);
      #pragma unroll
      for (int s = 0; s < 4; ++s) {
        const float4 a4 = *(const float4*)&als[s][w*64 + j4*4];  // broadcast
        g0[s] = fmaf(w0f, a4.x, g0[s]);
        g1[s] = fmaf(w1f, a4.y, g1[s]);
        g2[s] = fmaf(w2f, a4.z, g2[s]);
        g3[s] = fmaf(w3f, a4.w, g3[s]);
      }
    }
    #pragma unroll
    for (int s = 0; s < 4; ++s) {
      const float gl   = (g0[s] + g1[s]) + (g2[s] + g3[s]);
      const float gate = __builtin_amdgcn_rcpf(1.0f + __builtin_amdgcn_exp2f(-LOG2E * gl));
      const float fin  = fmaf(gate, att[s] - xv[s], xv[s]);
      if (val[s]) {
        OT[p[s]*64 + c] = fin;             // coalesced full-line (N,C) store
        pacc += fin;
      }
    }
  }

  // pool reduce: 4 waves -> 64 lanes -> 64 device atomics
  als[0][t] = pacc;
  __syncthreads();
  if (t < 64) {
    float s = als[0][t] + als[0][64 + t] + als[0][128 + t] + als[0][192 + t];
    atomicAdd(&pool[b*64 + t], s);
  }
}

// ---------------------------------------------------------------------------
// Kernel 3: (N,C) -> (B,C,N) transpose through padded LDS (full-line reads
// AND writes). Block 0 additionally runs the GRU cell.
// ---------------------------------------------------------------------------
__global__ __launch_bounds__(256) void outpool_kernel(
    const float* __restrict__ OT, float* __restrict__ out,
    const float* __restrict__ pool, const float* __restrict__ prev,
    const float* __restrict__ W_ih, const float* __restrict__ W_hh,
    const float* __restrict__ b_ih, const float* __restrict__ b_hh,
    float* __restrict__ outmem)
{
  __shared__ __align__(16) float ls[64*65];
  __shared__ __align__(16) float mu[128];
  __shared__ float gi[384];
  __shared__ float gh[384];
  const int t  = threadIdx.x;
  const int bi = blockIdx.x;
  const int b  = bi / 216;
  const int n0 = (bi - b*216) * 64;
  #pragma unroll
  for (int i = 0; i < 16; ++i) {
    int u = i*256 + t;
    int pos = u >> 6, cc = u & 63;
    ls[cc*65 + pos] = OT[(size_t)(b*NPOS + n0 + pos)*64 + cc];  // coalesced read
  }
  if (bi == 0 && t < 128) mu[t] = pool[t] * (1.0f / (float)NPOS);
  __syncthreads();
  #pragma unroll
  for (int i = 0; i < 16; ++i) {
    int u = i*256 + t;
    int cc = u >> 6, j = u & 63;
    out[(size_t)(b*64 + cc)*NPOS + n0 + j] = ls[cc*65 + j];     // coalesced write
  }
  if (bi != 0) return;

  // ---- GRU cell (block 0 only) ----
  for (int r = t; r < 384; r += 256) {
    const int b2 = r / 192, j = r - b2*192;
    const float4* wi4 = (const float4*)(W_ih + (size_t)j*64);
    const float4* wh4 = (const float4*)(W_hh + (size_t)j*64);
    const float4* mu4 = (const float4*)(mu + b2*64);
    const float4* pv4 = (const float4*)(prev + b2*64);
    float sgi = b_ih[j], sgh = b_hh[j];
    #pragma unroll
    for (int k = 0; k < 16; ++k) {
      float4 wv = wi4[k], m4 = mu4[k];
      sgi = fmaf(wv.x, m4.x, sgi); sgi = fmaf(wv.y, m4.y, sgi);
      sgi = fmaf(wv.z, m4.z, sgi); sgi = fmaf(wv.w, m4.w, sgi);
      float4 hv = wh4[k], p4 = pv4[k];
      sgh = fmaf(hv.x, p4.x, sgh); sgh = fmaf(hv.y, p4.y, sgh);
      sgh = fmaf(hv.z, p4.z, sgh); sgh = fmaf(hv.w, p4.w, sgh);
    }
    gi[r] = sgi; gh[r] = sgh;
  }
  __syncthreads();
  if (t < 128) {
    const int b2 = t >> 6, cc = t & 63;
    float ir = gi[b2*192 + cc],       hr = gh[b2*192 + cc];
    float iz = gi[b2*192 + 64 + cc],  hz = gh[b2*192 + 64 + cc];
    float ii = gi[b2*192 + 128 + cc], hn = gh[b2*192 + 128 + cc];
    float rr = 1.0f / (1.0f + __builtin_amdgcn_exp2f(-LOG2E * (ir + hr)));
    float zz = 1.0f / (1.0f + __builtin_amdgcn_exp2f(-LOG2E * (iz + hz)));
    float ng = tanhf(ii + rr * hn);
    outmem[t] = (1.0f - zz) * ng + zz * prev[t];
  }
}

// ---------------------------------------------------------------------------
extern "C" void kernel_launch(void* const* d_in, const int* in_sizes, int n_in,
                              void* d_out, int out_size, void* d_ws, size_t ws_size,
                              hipStream_t stream) {
  const float* x    = (const float*)d_in[0];
  const float* prev = (const float*)d_in[1];
  const float* Wq   = (const float*)d_in[2];
  const float* bq   = (const float*)d_in[3];
  const float* Wk   = (const float*)d_in[4];
  const float* bk   = (const float*)d_in[5];
  const float* Wv   = (const float*)d_in[6];
  const float* bv   = (const float*)d_in[7];
  const float* memk = (const float*)d_in[8];
  const float* memv = (const float*)d_in[9];
  const float* Wg   = (const float*)d_in[10];
  const float* bg   = (const float*)d_in[11];
  const float* W_ih = (const float*)d_in[12];
  const float* W_hh = (const float*)d_in[13];
  const float* b_ih = (const float*)d_in[14];
  const float* b_hh = (const float*)d_in[15];

  float* out    = (float*)d_out;                 // (B,C,H,D,W)
  float* outmem = out + (size_t)BTCH*CDIM*NPOS;  // (B,C)

  const size_t SZ = (size_t)BTCH*NPOS*CDIM;      // 1769472
  float* wsf        = (float*)d_ws;
  float* OT         = wsf;                       // attn result (N,C)
  unsigned int* KVp = (unsigned int*)(wsf + SZ); // bf16 K|V packed
  float* QGX        = wsf + 2*SZ;                // 2 floats per (p,c)
  float* pool       = wsf + 4*SZ;                // 128 floats

  qkvg_kernel<<<BTCH*216, 256, 0, stream>>>(x, Wq, bq, Wk, bk, Wv, bv, Wg,
                                            KVp, QGX, pool);
  attn_kernel<<<BTCH*512, 256, 0, stream>>>(OT, KVp, QGX,
                                            bk, bv, memk, memv, Wg, bg, pool);
  outpool_kernel<<<BTCH*216, 256, 0, stream>>>(OT, out, pool, prev,
                                               W_ih, W_hh, b_ih, b_hh, outmem);
}

// Round 9
// 188.735 us; speedup vs baseline: 1.2875x; 1.2875x over previous
//
#include <hip/hip_runtime.h>
#include <math.h>

#define NPOS 13824   // 24*24*24
#define CDIM 64
#define BTCH 2
#define LOG2E 1.4426950408889634f
#define QSCALE (0.125f * LOG2E)

__device__ __forceinline__ unsigned int f2bf1(float f) {   // RNE float->bf16
  unsigned int u = __float_as_uint(f);
  return (u + 0x7FFFu + ((u >> 16) & 1u)) >> 16;
}

// ---------------------------------------------------------------------------
// Kernel 1: projections. Outputs (B,N,C): KVp = bf16 K|V packed (bias incl.),
// QGX = {bf16 q(prescaled)|gateX, fp32 x} 8 B records. Zeroes pool.
// ---------------------------------------------------------------------------
__global__ __launch_bounds__(256) void qkvg_kernel(
    const float* __restrict__ x,
    const float* __restrict__ Wq, const float* __restrict__ bq,
    const float* __restrict__ Wk, const float* __restrict__ bk,
    const float* __restrict__ Wv, const float* __restrict__ bv,
    const float* __restrict__ Wg,
    unsigned int* __restrict__ KVp, float* __restrict__ QGX,
    float* __restrict__ pool)
{
  __shared__ __align__(16) float wqt[64*68];
  __shared__ __align__(16) float wkt[64*68];
  __shared__ __align__(16) float wvt[64*68];
  __shared__ __align__(16) float wgt[64*68];
  const int t  = threadIdx.x;
  const int bi = blockIdx.x;
  const int b  = bi / 216;
  const int n0 = (bi - b*216) * 64;
  if (bi == 0 && t < 128) pool[t] = 0.0f;

  #pragma unroll
  for (int k = 0; k < 16; ++k) {
    int idx = t + k*256;                 // 0..4095
    int lo = idx & 63, hi = idx >> 6;
    wqt[lo*68 + hi] = Wq[idx] * QSCALE;  // [c_in][c_out], Q pre-scaled
    wkt[lo*68 + hi] = Wk[idx];
    wvt[lo*68 + hi] = Wv[idx];
    wgt[lo*68 + hi] = Wg[hi*128 + lo];   // first 64 columns of Wg
  }
  __syncthreads();

  const int c0  = (t & 15) * 4;          // 4 output channels
  const int nn0 = (t >> 4) * 4;          // 4 positions
  const float* xbase = x + (size_t)(b*64)*NPOS + n0 + nn0;
  float aq[4][4] = {}; float ak[4][4] = {}; float av[4][4] = {}; float ag[4][4] = {};
  #pragma unroll 4
  for (int cp = 0; cp < 64; ++cp) {
    const float4 xv4 = *(const float4*)(xbase + (size_t)cp*NPOS);
    const float4 q4  = *(const float4*)&wqt[cp*68 + c0];
    const float4 k4  = *(const float4*)&wkt[cp*68 + c0];
    const float4 v4  = *(const float4*)&wvt[cp*68 + c0];
    const float4 g4  = *(const float4*)&wgt[cp*68 + c0];
    const float xa[4] = {xv4.x, xv4.y, xv4.z, xv4.w};
    const float qa[4] = {q4.x, q4.y, q4.z, q4.w};
    const float ka[4] = {k4.x, k4.y, k4.z, k4.w};
    const float va[4] = {v4.x, v4.y, v4.z, v4.w};
    const float ga[4] = {g4.x, g4.y, g4.z, g4.w};
    #pragma unroll
    for (int ci = 0; ci < 4; ++ci)
      #pragma unroll
      for (int ni = 0; ni < 4; ++ni) {
        aq[ci][ni] = fmaf(qa[ci], xa[ni], aq[ci][ni]);
        ak[ci][ni] = fmaf(ka[ci], xa[ni], ak[ci][ni]);
        av[ci][ni] = fmaf(va[ci], xa[ni], av[ci][ni]);
        ag[ci][ni] = fmaf(ga[ci], xa[ni], ag[ci][ni]);
      }
  }
  // re-read x tile rows c0..c0+3 (L1-hot) for the x field of QGX
  float4 xr[4];
  #pragma unroll
  for (int e = 0; e < 4; ++e)
    xr[e] = *(const float4*)(x + (size_t)(b*64 + c0 + e)*NPOS + n0 + nn0);
  const float xre[4][4] = {{xr[0].x,xr[0].y,xr[0].z,xr[0].w},
                           {xr[1].x,xr[1].y,xr[1].z,xr[1].w},
                           {xr[2].x,xr[2].y,xr[2].z,xr[2].w},
                           {xr[3].x,xr[3].y,xr[3].z,xr[3].w}};
  const float4 bq4 = *(const float4*)&bq[c0];
  const float4 bk4 = *(const float4*)&bk[c0];
  const float4 bv4 = *(const float4*)&bv[c0];
  const float bqa[4] = {bq4.x, bq4.y, bq4.z, bq4.w};
  const float bka[4] = {bk4.x, bk4.y, bk4.z, bk4.w};
  const float bva[4] = {bv4.x, bv4.y, bv4.z, bv4.w};
  #pragma unroll
  for (int ni = 0; ni < 4; ++ni) {
    const int p = b*NPOS + n0 + nn0 + ni;   // (N,C) layout: [p*64 + c]
    uint4 kv;                               // bf16 K (hi) | V (lo), bias incl.
    kv.x = (f2bf1(ak[0][ni]+bka[0]) << 16) | f2bf1(av[0][ni]+bva[0]);
    kv.y = (f2bf1(ak[1][ni]+bka[1]) << 16) | f2bf1(av[1][ni]+bva[1]);
    kv.z = (f2bf1(ak[2][ni]+bka[2]) << 16) | f2bf1(av[2][ni]+bva[2]);
    kv.w = (f2bf1(ak[3][ni]+bka[3]) << 16) | f2bf1(av[3][ni]+bva[3]);
    *(uint4*)&KVp[p*64 + c0] = kv;
    // QGX: {bf16 q|gateX, x} per (p,c)
    unsigned pk0 = (f2bf1(fmaf(bqa[0], QSCALE, aq[0][ni])) << 16) | f2bf1(ag[0][ni]);
    unsigned pk1 = (f2bf1(fmaf(bqa[1], QSCALE, aq[1][ni])) << 16) | f2bf1(ag[1][ni]);
    unsigned pk2 = (f2bf1(fmaf(bqa[2], QSCALE, aq[2][ni])) << 16) | f2bf1(ag[2][ni]);
    unsigned pk3 = (f2bf1(fmaf(bqa[3], QSCALE, aq[3][ni])) << 16) | f2bf1(ag[3][ni]);
    float4 o;
    o = make_float4(__uint_as_float(pk0), xre[0][ni], __uint_as_float(pk1), xre[1][ni]);
    *(float4*)&QGX[(size_t)(p*64 + c0)*2]     = o;
    o = make_float4(__uint_as_float(pk2), xre[2][ni], __uint_as_float(pk3), xre[3][ni]);
    *(float4*)&QGX[(size_t)(p*64 + c0)*2 + 4] = o;
  }
}

// ---------------------------------------------------------------------------
// Kernel 2: tiled attention (R7 2-position structure — no spill). Halo in
// LDS as [c][slot] rows (stride 129): the 27 neighbor reads are immediate
// offsets off one base -> ds_read2_b32 pairing. Gate weights bf16-packed in
// VGPRs. Coalesced (N,C) result into OT.
// ---------------------------------------------------------------------------
__global__ __launch_bounds__(256, 4) void attn_kernel(
    float* __restrict__ OT,
    const unsigned int* __restrict__ KVp,
    const float* __restrict__ QGX,
    const float* __restrict__ bk, const float* __restrict__ bv,
    const float* __restrict__ memk, const float* __restrict__ memv,
    const float* __restrict__ Wg, const float* __restrict__ bg,
    float* __restrict__ pool)
{
  __shared__ __align__(16) unsigned int kvbuf[64*129]; // [c][slot0..124]
  __shared__ __align__(16) float alsA[256];
  __shared__ __align__(16) float alsB[256];
  const int t = threadIdx.x;
  const int c = t & 63;
  const int w = t >> 6;

  // stage Wg[:,64:] via padded-65 LDS transpose (overlay kvbuf), pack to bf16
  {
    float* wgt2 = (float*)kvbuf;
    #pragma unroll
    for (int k = 0; k < 16; ++k) {
      int u = t + k*256;
      int cp = u >> 6, j = u & 63;
      wgt2[j*65 + cp] = Wg[cp*128 + 64 + j];
    }
  }
  __syncthreads();
  unsigned int wg2p[32];                 // bf16 pair: lo=even j, hi=odd j
  {
    const float* wgt2 = (const float*)kvbuf;
    #pragma unroll
    for (int j2 = 0; j2 < 32; ++j2) {
      unsigned lo = f2bf1(wgt2[(2*j2)*65 + c]);
      unsigned hi = f2bf1(wgt2[(2*j2+1)*65 + c]);
      wg2p[j2] = lo | (hi << 16);
    }
  }
  float mk[5], mv[5];
  #pragma unroll
  for (int m = 0; m < 5; ++m) { mk[m] = memk[c*5 + m]; mv[m] = memv[c*5 + m]; }
  const float bg_c = bg[c];
  const unsigned bias_kv = (f2bf1(bk[c]) << 16) | f2bf1(bv[c]);
  __syncthreads();

  // XCD-aware swizzle: bi&7 = XCD; contiguous 128-tile slab per XCD
  const int bi = (int)(blockIdx.x & 7) * 128 + (int)(blockIdx.x >> 3);
  const int b  = bi >> 9;                 // 512 tiles (8x8x8) per batch
  const int tb = bi & 511;
  const int h0 = (tb >> 6) * 3;
  const int d0 = ((tb >> 3) & 7) * 3;
  const int w0 = (tb & 7) * 3;
  const int bN = b * NPOS;

  // stage 5x5x5 halo into [c][slot] rows; pos wave-uniform, lane = channel
  for (int u = t; u < 8000; u += 256) {
    const int pos = u >> 6;               // wave-uniform
    const int ph = pos / 25, pr = pos - ph*25;
    const int pd = pr / 5,  pw = pr - pd*5;
    const int hh = h0 - 1 + ph, dd = d0 - 1 + pd, ww = w0 - 1 + pw;
    const bool inb = ((unsigned)hh < 24u) && ((unsigned)dd < 24u) && ((unsigned)ww < 24u);
    unsigned kv = bias_kv;
    if (inb) kv = KVp[(size_t)(bN + hh*576 + dd*24 + ww)*64 + c];
    kvbuf[c*129 + pos] = kv;              // stride 129 == 1 mod 32: conflict-free
  }
  __syncthreads();

  float pacc = 0.0f;
  // two positions (li, li+4) per iteration; independent chains for ILP
  for (int li = w; li < 27; li += 8) {
    const int liB0 = li + 4;
    const bool hasB = liB0 < 27;          // wave-uniform
    const int liB = hasB ? liB0 : li;

    const int lhA = li / 9,  lrA = li - lhA*9;
    const int ldA = lrA / 3, lwA = lrA - ldA*3;
    const int pA  = bN + (h0+lhA)*576 + (d0+ldA)*24 + (w0+lwA);
    const unsigned int* kvA = &kvbuf[c*129 + lhA*25 + ldA*5 + lwA];
    const int lhB = liB / 9,  lrB = liB - lhB*9;
    const int ldB = lrB / 3,  lwB = lrB - ldB*3;
    const int pB  = bN + (h0+lhB)*576 + (d0+ldB)*24 + (w0+lwB);
    const unsigned int* kvB = &kvbuf[c*129 + lhB*25 + ldB*5 + lwB];

    const float2 gqA = *(const float2*)&QGX[(size_t)(pA*64 + c)*2];
    const float2 gqB = *(const float2*)&QGX[(size_t)(pB*64 + c)*2];
    const unsigned uqA = __float_as_uint(gqA.x);
    const unsigned uqB = __float_as_uint(gqB.x);
    const float qA  = __uint_as_float(uqA & 0xFFFF0000u);
    const float gxA = __uint_as_float(uqA << 16);
    const float xvA = gqA.y;
    const float qB  = __uint_as_float(uqB & 0xFFFF0000u);
    const float gxB = __uint_as_float(uqB << 16);
    const float xvB = gqB.y;

    // single-pass softmax (no max subtraction; |logit| <= ~2)
    float sA0 = 0.f, sA1 = 0.f, oA0 = 0.f, oA1 = 0.f;
    float sB0 = 0.f, sB1 = 0.f, oB0 = 0.f, oB1 = 0.f;
    #pragma unroll
    for (int m = 0; m < 5; ++m) {
      const float pfA = __builtin_amdgcn_exp2f(qA * mk[m]);
      const float pfB = __builtin_amdgcn_exp2f(qB * mk[m]);
      if (m & 1) { sA1 += pfA; oA1 = fmaf(pfA, mv[m], oA1);
                   sB1 += pfB; oB1 = fmaf(pfB, mv[m], oB1); }
      else       { sA0 += pfA; oA0 = fmaf(pfA, mv[m], oA0);
                   sB0 += pfB; oB0 = fmaf(pfB, mv[m], oB0); }
    }
    #pragma unroll
    for (int i = 0; i < 3; ++i)
      #pragma unroll
      for (int j = 0; j < 3; ++j)
        #pragma unroll
        for (int l = 0; l < 3; ++l) {
          const int s4  = i*9 + j*3 + l;
          const int off = i*25 + j*5 + l;     // immediate 0..62 -> ds_read2
          const unsigned a = kvA[off], bb2 = kvB[off];
          const float kA = __uint_as_float(a & 0xFFFF0000u);
          const float vA = __uint_as_float(a << 16);
          const float kB = __uint_as_float(bb2 & 0xFFFF0000u);
          const float vB = __uint_as_float(bb2 << 16);
          const float pfA = __builtin_amdgcn_exp2f(qA * kA);
          const float pfB = __builtin_amdgcn_exp2f(qB * kB);
          if (s4 & 1) { sA1 += pfA; oA1 = fmaf(pfA, vA, oA1);
                        sB1 += pfB; oB1 = fmaf(pfB, vB, oB1); }
          else        { sA0 += pfA; oA0 = fmaf(pfA, vA, oA0);
                        sB0 += pfB; oB0 = fmaf(pfB, vB, oB0); }
        }
    const float attA = (oA0 + oA1) * __builtin_amdgcn_rcpf(sA0 + sA1);
    const float attB = (oB0 + oB1) * __builtin_amdgcn_rcpf(sB0 + sB1);

    alsA[w*64 + c] = attA;                // wave-local broadcast buffers
    alsB[w*64 + c] = attB;
    float gA0 = gxA + bg_c, gA1 = 0.f, gA2 = 0.f, gA3 = 0.f;
    float gB0 = gxB + bg_c, gB1 = 0.f, gB2 = 0.f, gB3 = 0.f;
    #pragma unroll
    for (int j4 = 0; j4 < 16; ++j4) {
      const float4 a4 = *(const float4*)&alsA[w*64 + j4*4];
      const float4 b4 = *(const float4*)&alsB[w*64 + j4*4];
      const unsigned pk0 = wg2p[2*j4], pk1 = wg2p[2*j4+1];
      const float w0f = __uint_as_float(pk0 << 16);
      const float w1f = __uint_as_float(pk0 & 0xFFFF0000u);
      const float w2f = __uint_as_float(pk1 << 16);
      const float w3f = __uint_as_float(pk1 & 0xFFFF0000u);
      gA0 = fmaf(w0f, a4.x, gA0); gB0 = fmaf(w0f, b4.x, gB0);
      gA1 = fmaf(w1f, a4.y, gA1); gB1 = fmaf(w1f, b4.y, gB1);
      gA2 = fmaf(w2f, a4.z, gA2); gB2 = fmaf(w2f, b4.z, gB2);
      gA3 = fmaf(w3f, a4.w, gA3); gB3 = fmaf(w3f, b4.w, gB3);
    }
    const float glA   = (gA0 + gA1) + (gA2 + gA3);
    const float glB   = (gB0 + gB1) + (gB2 + gB3);
    const float gateA = __builtin_amdgcn_rcpf(1.0f + __builtin_amdgcn_exp2f(-LOG2E * glA));
    const float gateB = __builtin_amdgcn_rcpf(1.0f + __builtin_amdgcn_exp2f(-LOG2E * glB));
    const float finA  = fmaf(gateA, attA - xvA, xvA);
    const float finB  = fmaf(gateB, attB - xvB, xvB);
    OT[pA*64 + c] = finA;                 // coalesced full-line (N,C) stores
    pacc += finA;
    if (hasB) { OT[pB*64 + c] = finB; pacc += finB; }
  }

  // pool reduce: 4 waves -> 64 lanes -> 64 device atomics
  alsA[t] = pacc;
  __syncthreads();
  if (t < 64) {
    float s = alsA[t] + alsA[64 + t] + alsA[128 + t] + alsA[192 + t];
    atomicAdd(&pool[b*64 + t], s);
  }
}

// ---------------------------------------------------------------------------
// Kernel 3: (N,C) -> (B,C,N) transpose through padded LDS (full-line reads
// AND writes). Block 0 additionally runs the GRU cell.
// ---------------------------------------------------------------------------
__global__ __launch_bounds__(256) void outpool_kernel(
    const float* __restrict__ OT, float* __restrict__ out,
    const float* __restrict__ pool, const float* __restrict__ prev,
    const float* __restrict__ W_ih, const float* __restrict__ W_hh,
    const float* __restrict__ b_ih, const float* __restrict__ b_hh,
    float* __restrict__ outmem)
{
  __shared__ __align__(16) float ls[64*65];
  __shared__ __align__(16) float mu[128];
  __shared__ float gi[384];
  __shared__ float gh[384];
  const int t  = threadIdx.x;
  const int bi = blockIdx.x;
  const int b  = bi / 216;
  const int n0 = (bi - b*216) * 64;
  #pragma unroll
  for (int i = 0; i < 16; ++i) {
    int u = i*256 + t;
    int pos = u >> 6, cc = u & 63;
    ls[cc*65 + pos] = OT[(size_t)(b*NPOS + n0 + pos)*64 + cc];  // coalesced read
  }
  if (bi == 0 && t < 128) mu[t] = pool[t] * (1.0f / (float)NPOS);
  __syncthreads();
  #pragma unroll
  for (int i = 0; i < 16; ++i) {
    int u = i*256 + t;
    int cc = u >> 6, j = u & 63;
    out[(size_t)(b*64 + cc)*NPOS + n0 + j] = ls[cc*65 + j];     // coalesced write
  }
  if (bi != 0) return;

  // ---- GRU cell (block 0 only) ----
  for (int r = t; r < 384; r += 256) {
    const int b2 = r / 192, j = r - b2*192;
    const float4* wi4 = (const float4*)(W_ih + (size_t)j*64);
    const float4* wh4 = (const float4*)(W_hh + (size_t)j*64);
    const float4* mu4 = (const float4*)(mu + b2*64);
    const float4* pv4 = (const float4*)(prev + b2*64);
    float sgi = b_ih[j], sgh = b_hh[j];
    #pragma unroll
    for (int k = 0; k < 16; ++k) {
      float4 wv = wi4[k], m4 = mu4[k];
      sgi = fmaf(wv.x, m4.x, sgi); sgi = fmaf(wv.y, m4.y, sgi);
      sgi = fmaf(wv.z, m4.z, sgi); sgi = fmaf(wv.w, m4.w, sgi);
      float4 hv = wh4[k], p4 = pv4[k];
      sgh = fmaf(hv.x, p4.x, sgh); sgh = fmaf(hv.y, p4.y, sgh);
      sgh = fmaf(hv.z, p4.z, sgh); sgh = fmaf(hv.w, p4.w, sgh);
    }
    gi[r] = sgi; gh[r] = sgh;
  }
  __syncthreads();
  if (t < 128) {
    const int b2 = t >> 6, cc = t & 63;
    float ir = gi[b2*192 + cc],       hr = gh[b2*192 + cc];
    float iz = gi[b2*192 + 64 + cc],  hz = gh[b2*192 + 64 + cc];
    float ii = gi[b2*192 + 128 + cc], hn = gh[b2*192 + 128 + cc];
    float rr = 1.0f / (1.0f + __builtin_amdgcn_exp2f(-LOG2E * (ir + hr)));
    float zz = 1.0f / (1.0f + __builtin_amdgcn_exp2f(-LOG2E * (iz + hz)));
    float ng = tanhf(ii + rr * hn);
    outmem[t] = (1.0f - zz) * ng + zz * prev[t];
  }
}

// ---------------------------------------------------------------------------
extern "C" void kernel_launch(void* const* d_in, const int* in_sizes, int n_in,
                              void* d_out, int out_size, void* d_ws, size_t ws_size,
                              hipStream_t stream) {
  const float* x    = (const float*)d_in[0];
  const float* prev = (const float*)d_in[1];
  const float* Wq   = (const float*)d_in[2];
  const float* bq   = (const float*)d_in[3];
  const float* Wk   = (const float*)d_in[4];
  const float* bk   = (const float*)d_in[5];
  const float* Wv   = (const float*)d_in[6];
  const float* bv   = (const float*)d_in[7];
  const float* memk = (const float*)d_in[8];
  const float* memv = (const float*)d_in[9];
  const float* Wg   = (const float*)d_in[10];
  const float* bg   = (const float*)d_in[11];
  const float* W_ih = (const float*)d_in[12];
  const float* W_hh = (const float*)d_in[13];
  const float* b_ih = (const float*)d_in[14];
  const float* b_hh = (const float*)d_in[15];

  float* out    = (float*)d_out;                 // (B,C,H,D,W)
  float* outmem = out + (size_t)BTCH*CDIM*NPOS;  // (B,C)

  const size_t SZ = (size_t)BTCH*NPOS*CDIM;      // 1769472
  float* wsf        = (float*)d_ws;
  float* OT         = wsf;                       // attn result (N,C)
  unsigned int* KVp = (unsigned int*)(wsf + SZ); // bf16 K|V packed
  float* QGX        = wsf + 2*SZ;                // 2 floats per (p,c)
  float* pool       = wsf + 4*SZ;                // 128 floats

  qkvg_kernel<<<BTCH*216, 256, 0, stream>>>(x, Wq, bq, Wk, bk, Wv, bv, Wg,
                                            KVp, QGX, pool);
  attn_kernel<<<BTCH*512, 256, 0, stream>>>(OT, KVp, QGX,
                                            bk, bv, memk, memv, Wg, bg, pool);
  outpool_kernel<<<BTCH*216, 256, 0, stream>>>(OT, out, pool, prev,
                                               W_ih, W_hh, b_ih, b_hh, outmem);
}

// Round 10
// 165.677 us; speedup vs baseline: 1.4667x; 1.1392x over previous
//
#include <hip/hip_runtime.h>
#include <math.h>

#define NPOS 13824   // 24*24*24
#define CDIM 64
#define BTCH 2
#define LOG2E 1.4426950408889634f
#define QSCALE (0.125f * LOG2E)

__device__ __forceinline__ unsigned int f2bf1(float f) {   // RNE float->bf16
  unsigned int u = __float_as_uint(f);
  return (u + 0x7FFFu + ((u >> 16) & 1u)) >> 16;
}

// ---------------------------------------------------------------------------
// Kernel 1: projections. Outputs (B,N,C): KVp = bf16 K|V packed (bias incl.),
// QGX = {bf16 q(prescaled)|gateX, fp32 x} 8 B records. Zeroes pool.
// ---------------------------------------------------------------------------
__global__ __launch_bounds__(256) void qkvg_kernel(
    const float* __restrict__ x,
    const float* __restrict__ Wq, const float* __restrict__ bq,
    const float* __restrict__ Wk, const float* __restrict__ bk,
    const float* __restrict__ Wv, const float* __restrict__ bv,
    const float* __restrict__ Wg,
    unsigned int* __restrict__ KVp, float* __restrict__ QGX,
    float* __restrict__ pool)
{
  __shared__ __align__(16) float wqt[64*68];
  __shared__ __align__(16) float wkt[64*68];
  __shared__ __align__(16) float wvt[64*68];
  __shared__ __align__(16) float wgt[64*68];
  const int t  = threadIdx.x;
  const int bi = blockIdx.x;
  const int b  = bi / 216;
  const int n0 = (bi - b*216) * 64;
  if (bi == 0 && t < 128) pool[t] = 0.0f;

  #pragma unroll
  for (int k = 0; k < 16; ++k) {
    int idx = t + k*256;                 // 0..4095
    int lo = idx & 63, hi = idx >> 6;
    wqt[lo*68 + hi] = Wq[idx] * QSCALE;  // [c_in][c_out], Q pre-scaled
    wkt[lo*68 + hi] = Wk[idx];
    wvt[lo*68 + hi] = Wv[idx];
    wgt[lo*68 + hi] = Wg[hi*128 + lo];   // first 64 columns of Wg
  }
  __syncthreads();

  const int c0  = (t & 15) * 4;          // 4 output channels
  const int nn0 = (t >> 4) * 4;          // 4 positions
  const float* xbase = x + (size_t)(b*64)*NPOS + n0 + nn0;
  float aq[4][4] = {}; float ak[4][4] = {}; float av[4][4] = {}; float ag[4][4] = {};
  #pragma unroll 4
  for (int cp = 0; cp < 64; ++cp) {
    const float4 xv4 = *(const float4*)(xbase + (size_t)cp*NPOS);
    const float4 q4  = *(const float4*)&wqt[cp*68 + c0];
    const float4 k4  = *(const float4*)&wkt[cp*68 + c0];
    const float4 v4  = *(const float4*)&wvt[cp*68 + c0];
    const float4 g4  = *(const float4*)&wgt[cp*68 + c0];
    const float xa[4] = {xv4.x, xv4.y, xv4.z, xv4.w};
    const float qa[4] = {q4.x, q4.y, q4.z, q4.w};
    const float ka[4] = {k4.x, k4.y, k4.z, k4.w};
    const float va[4] = {v4.x, v4.y, v4.z, v4.w};
    const float ga[4] = {g4.x, g4.y, g4.z, g4.w};
    #pragma unroll
    for (int ci = 0; ci < 4; ++ci)
      #pragma unroll
      for (int ni = 0; ni < 4; ++ni) {
        aq[ci][ni] = fmaf(qa[ci], xa[ni], aq[ci][ni]);
        ak[ci][ni] = fmaf(ka[ci], xa[ni], ak[ci][ni]);
        av[ci][ni] = fmaf(va[ci], xa[ni], av[ci][ni]);
        ag[ci][ni] = fmaf(ga[ci], xa[ni], ag[ci][ni]);
      }
  }
  // re-read x tile rows c0..c0+3 (L1-hot) for the x field of QGX
  float4 xr[4];
  #pragma unroll
  for (int e = 0; e < 4; ++e)
    xr[e] = *(const float4*)(x + (size_t)(b*64 + c0 + e)*NPOS + n0 + nn0);
  const float xre[4][4] = {{xr[0].x,xr[0].y,xr[0].z,xr[0].w},
                           {xr[1].x,xr[1].y,xr[1].z,xr[1].w},
                           {xr[2].x,xr[2].y,xr[2].z,xr[2].w},
                           {xr[3].x,xr[3].y,xr[3].z,xr[3].w}};
  const float4 bq4 = *(const float4*)&bq[c0];
  const float4 bk4 = *(const float4*)&bk[c0];
  const float4 bv4 = *(const float4*)&bv[c0];
  const float bqa[4] = {bq4.x, bq4.y, bq4.z, bq4.w};
  const float bka[4] = {bk4.x, bk4.y, bk4.z, bk4.w};
  const float bva[4] = {bv4.x, bv4.y, bv4.z, bv4.w};
  #pragma unroll
  for (int ni = 0; ni < 4; ++ni) {
    const int p = b*NPOS + n0 + nn0 + ni;   // (N,C) layout: [p*64 + c]
    uint4 kv;                               // bf16 K (hi) | V (lo), bias incl.
    kv.x = (f2bf1(ak[0][ni]+bka[0]) << 16) | f2bf1(av[0][ni]+bva[0]);
    kv.y = (f2bf1(ak[1][ni]+bka[1]) << 16) | f2bf1(av[1][ni]+bva[1]);
    kv.z = (f2bf1(ak[2][ni]+bka[2]) << 16) | f2bf1(av[2][ni]+bva[2]);
    kv.w = (f2bf1(ak[3][ni]+bka[3]) << 16) | f2bf1(av[3][ni]+bva[3]);
    *(uint4*)&KVp[p*64 + c0] = kv;
    // QGX: {bf16 q|gateX, x} per (p,c)
    unsigned pk0 = (f2bf1(fmaf(bqa[0], QSCALE, aq[0][ni])) << 16) | f2bf1(ag[0][ni]);
    unsigned pk1 = (f2bf1(fmaf(bqa[1], QSCALE, aq[1][ni])) << 16) | f2bf1(ag[1][ni]);
    unsigned pk2 = (f2bf1(fmaf(bqa[2], QSCALE, aq[2][ni])) << 16) | f2bf1(ag[2][ni]);
    unsigned pk3 = (f2bf1(fmaf(bqa[3], QSCALE, aq[3][ni])) << 16) | f2bf1(ag[3][ni]);
    float4 o;
    o = make_float4(__uint_as_float(pk0), xre[0][ni], __uint_as_float(pk1), xre[1][ni]);
    *(float4*)&QGX[(size_t)(p*64 + c0)*2]     = o;
    o = make_float4(__uint_as_float(pk2), xre[2][ni], __uint_as_float(pk3), xre[3][ni]);
    *(float4*)&QGX[(size_t)(p*64 + c0)*2 + 4] = o;
  }
}

// ---------------------------------------------------------------------------
// Kernel 2: tiled attention. NOTE: no min-waves launch-bound — with (256,4)
// the allocator pinned VGPR=64 and spilled ~75 MB/dispatch to scratch
// (R8/R9 counters). LDS (35.3 KB) already caps occupancy at 4 blocks/CU, so
// letting VGPR float costs nothing. Halo in LDS as [c][slot] rows (stride
// 129): 27 neighbor reads are immediate offsets -> ds_read2_b32 pairing.
// 2-position ILP. Gate weights bf16-packed in VGPRs. Coalesced (N,C) out.
// ---------------------------------------------------------------------------
__global__ __launch_bounds__(256) void attn_kernel(
    float* __restrict__ OT,
    const unsigned int* __restrict__ KVp,
    const float* __restrict__ QGX,
    const float* __restrict__ bk, const float* __restrict__ bv,
    const float* __restrict__ memk, const float* __restrict__ memv,
    const float* __restrict__ Wg, const float* __restrict__ bg,
    float* __restrict__ pool)
{
  __shared__ __align__(16) unsigned int kvbuf[64*129]; // [c][slot0..124]
  __shared__ __align__(16) float alsA[256];
  __shared__ __align__(16) float alsB[256];
  const int t = threadIdx.x;
  const int c = t & 63;
  const int w = t >> 6;

  // stage Wg[:,64:] via padded-65 LDS transpose (overlay kvbuf), pack to bf16
  {
    float* wgt2 = (float*)kvbuf;
    #pragma unroll
    for (int k = 0; k < 16; ++k) {
      int u = t + k*256;
      int cp = u >> 6, j = u & 63;
      wgt2[j*65 + cp] = Wg[cp*128 + 64 + j];
    }
  }
  __syncthreads();
  unsigned int wg2p[32];                 // bf16 pair: lo=even j, hi=odd j
  {
    const float* wgt2 = (const float*)kvbuf;
    #pragma unroll
    for (int j2 = 0; j2 < 32; ++j2) {
      unsigned lo = f2bf1(wgt2[(2*j2)*65 + c]);
      unsigned hi = f2bf1(wgt2[(2*j2+1)*65 + c]);
      wg2p[j2] = lo | (hi << 16);
    }
  }
  float mk[5], mv[5];
  #pragma unroll
  for (int m = 0; m < 5; ++m) { mk[m] = memk[c*5 + m]; mv[m] = memv[c*5 + m]; }
  const float bg_c = bg[c];
  const unsigned bias_kv = (f2bf1(bk[c]) << 16) | f2bf1(bv[c]);
  __syncthreads();

  // XCD-aware swizzle: bi&7 = XCD; contiguous 128-tile slab per XCD
  const int bi = (int)(blockIdx.x & 7) * 128 + (int)(blockIdx.x >> 3);
  const int b  = bi >> 9;                 // 512 tiles (8x8x8) per batch
  const int tb = bi & 511;
  const int h0 = (tb >> 6) * 3;
  const int d0 = ((tb >> 3) & 7) * 3;
  const int w0 = (tb & 7) * 3;
  const int bN = b * NPOS;

  // stage 5x5x5 halo into [c][slot] rows; pos wave-uniform, lane = channel
  for (int u = t; u < 8000; u += 256) {
    const int pos = u >> 6;               // wave-uniform
    const int ph = pos / 25, pr = pos - ph*25;
    const int pd = pr / 5,  pw = pr - pd*5;
    const int hh = h0 - 1 + ph, dd = d0 - 1 + pd, ww = w0 - 1 + pw;
    const bool inb = ((unsigned)hh < 24u) && ((unsigned)dd < 24u) && ((unsigned)ww < 24u);
    unsigned kv = bias_kv;
    if (inb) kv = KVp[(size_t)(bN + hh*576 + dd*24 + ww)*64 + c];
    kvbuf[c*129 + pos] = kv;              // stride 129 == 1 mod 32: conflict-free
  }
  __syncthreads();

  float pacc = 0.0f;
  // two positions (li, li+4) per iteration; independent chains for ILP
  for (int li = w; li < 27; li += 8) {
    const int liB0 = li + 4;
    const bool hasB = liB0 < 27;          // wave-uniform
    const int liB = hasB ? liB0 : li;

    const int lhA = li / 9,  lrA = li - lhA*9;
    const int ldA = lrA / 3, lwA = lrA - ldA*3;
    const int pA  = bN + (h0+lhA)*576 + (d0+ldA)*24 + (w0+lwA);
    const unsigned int* kvA = &kvbuf[c*129 + lhA*25 + ldA*5 + lwA];
    const int lhB = liB / 9,  lrB = liB - lhB*9;
    const int ldB = lrB / 3,  lwB = lrB - ldB*3;
    const int pB  = bN + (h0+lhB)*576 + (d0+ldB)*24 + (w0+lwB);
    const unsigned int* kvB = &kvbuf[c*129 + lhB*25 + ldB*5 + lwB];

    const float2 gqA = *(const float2*)&QGX[(size_t)(pA*64 + c)*2];
    const float2 gqB = *(const float2*)&QGX[(size_t)(pB*64 + c)*2];
    const unsigned uqA = __float_as_uint(gqA.x);
    const unsigned uqB = __float_as_uint(gqB.x);
    const float qA  = __uint_as_float(uqA & 0xFFFF0000u);
    const float gxA = __uint_as_float(uqA << 16);
    const float xvA = gqA.y;
    const float qB  = __uint_as_float(uqB & 0xFFFF0000u);
    const float gxB = __uint_as_float(uqB << 16);
    const float xvB = gqB.y;

    // single-pass softmax (no max subtraction; |logit| <= ~2)
    float sA0 = 0.f, sA1 = 0.f, oA0 = 0.f, oA1 = 0.f;
    float sB0 = 0.f, sB1 = 0.f, oB0 = 0.f, oB1 = 0.f;
    #pragma unroll
    for (int m = 0; m < 5; ++m) {
      const float pfA = __builtin_amdgcn_exp2f(qA * mk[m]);
      const float pfB = __builtin_amdgcn_exp2f(qB * mk[m]);
      if (m & 1) { sA1 += pfA; oA1 = fmaf(pfA, mv[m], oA1);
                   sB1 += pfB; oB1 = fmaf(pfB, mv[m], oB1); }
      else       { sA0 += pfA; oA0 = fmaf(pfA, mv[m], oA0);
                   sB0 += pfB; oB0 = fmaf(pfB, mv[m], oB0); }
    }
    #pragma unroll
    for (int i = 0; i < 3; ++i)
      #pragma unroll
      for (int j = 0; j < 3; ++j)
        #pragma unroll
        for (int l = 0; l < 3; ++l) {
          const int s4  = i*9 + j*3 + l;
          const int off = i*25 + j*5 + l;     // immediate 0..62 -> ds_read2
          const unsigned a = kvA[off], bb2 = kvB[off];
          const float kA = __uint_as_float(a & 0xFFFF0000u);
          const float vA = __uint_as_float(a << 16);
          const float kB = __uint_as_float(bb2 & 0xFFFF0000u);
          const float vB = __uint_as_float(bb2 << 16);
          const float pfA = __builtin_amdgcn_exp2f(qA * kA);
          const float pfB = __builtin_amdgcn_exp2f(qB * kB);
          if (s4 & 1) { sA1 += pfA; oA1 = fmaf(pfA, vA, oA1);
                        sB1 += pfB; oB1 = fmaf(pfB, vB, oB1); }
          else        { sA0 += pfA; oA0 = fmaf(pfA, vA, oA0);
                        sB0 += pfB; oB0 = fmaf(pfB, vB, oB0); }
        }
    const float attA = (oA0 + oA1) * __builtin_amdgcn_rcpf(sA0 + sA1);
    const float attB = (oB0 + oB1) * __builtin_amdgcn_rcpf(sB0 + sB1);

    alsA[w*64 + c] = attA;                // wave-local broadcast buffers
    alsB[w*64 + c] = attB;
    float gA0 = gxA + bg_c, gA1 = 0.f, gA2 = 0.f, gA3 = 0.f;
    float gB0 = gxB + bg_c, gB1 = 0.f, gB2 = 0.f, gB3 = 0.f;
    #pragma unroll
    for (int j4 = 0; j4 < 16; ++j4) {
      const float4 a4 = *(const float4*)&alsA[w*64 + j4*4];
      const float4 b4 = *(const float4*)&alsB[w*64 + j4*4];
      const unsigned pk0 = wg2p[2*j4], pk1 = wg2p[2*j4+1];
      const float w0f = __uint_as_float(pk0 << 16);
      const float w1f = __uint_as_float(pk0 & 0xFFFF0000u);
      const float w2f = __uint_as_float(pk1 << 16);
      const float w3f = __uint_as_float(pk1 & 0xFFFF0000u);
      gA0 = fmaf(w0f, a4.x, gA0); gB0 = fmaf(w0f, b4.x, gB0);
      gA1 = fmaf(w1f, a4.y, gA1); gB1 = fmaf(w1f, b4.y, gB1);
      gA2 = fmaf(w2f, a4.z, gA2); gB2 = fmaf(w2f, b4.z, gB2);
      gA3 = fmaf(w3f, a4.w, gA3); gB3 = fmaf(w3f, b4.w, gB3);
    }
    const float glA   = (gA0 + gA1) + (gA2 + gA3);
    const float glB   = (gB0 + gB1) + (gB2 + gB3);
    const float gateA = __builtin_amdgcn_rcpf(1.0f + __builtin_amdgcn_exp2f(-LOG2E * glA));
    const float gateB = __builtin_amdgcn_rcpf(1.0f + __builtin_amdgcn_exp2f(-LOG2E * glB));
    const float finA  = fmaf(gateA, attA - xvA, xvA);
    const float finB  = fmaf(gateB, attB - xvB, xvB);
    OT[pA*64 + c] = finA;                 // coalesced full-line (N,C) stores
    pacc += finA;
    if (hasB) { OT[pB*64 + c] = finB; pacc += finB; }
  }

  // pool reduce: 4 waves -> 64 lanes -> 64 device atomics
  alsA[t] = pacc;
  __syncthreads();
  if (t < 64) {
    float s = alsA[t] + alsA[64 + t] + alsA[128 + t] + alsA[192 + t];
    atomicAdd(&pool[b*64 + t], s);
  }
}

// ---------------------------------------------------------------------------
// Kernel 3: (N,C) -> (B,C,N) transpose through padded LDS (full-line reads
// AND writes). Block 0 additionally runs the GRU cell.
// ---------------------------------------------------------------------------
__global__ __launch_bounds__(256) void outpool_kernel(
    const float* __restrict__ OT, float* __restrict__ out,
    const float* __restrict__ pool, const float* __restrict__ prev,
    const float* __restrict__ W_ih, const float* __restrict__ W_hh,
    const float* __restrict__ b_ih, const float* __restrict__ b_hh,
    float* __restrict__ outmem)
{
  __shared__ __align__(16) float ls[64*65];
  __shared__ __align__(16) float mu[128];
  __shared__ float gi[384];
  __shared__ float gh[384];
  const int t  = threadIdx.x;
  const int bi = blockIdx.x;
  const int b  = bi / 216;
  const int n0 = (bi - b*216) * 64;
  #pragma unroll
  for (int i = 0; i < 16; ++i) {
    int u = i*256 + t;
    int pos = u >> 6, cc = u & 63;
    ls[cc*65 + pos] = OT[(size_t)(b*NPOS + n0 + pos)*64 + cc];  // coalesced read
  }
  if (bi == 0 && t < 128) mu[t] = pool[t] * (1.0f / (float)NPOS);
  __syncthreads();
  #pragma unroll
  for (int i = 0; i < 16; ++i) {
    int u = i*256 + t;
    int cc = u >> 6, j = u & 63;
    out[(size_t)(b*64 + cc)*NPOS + n0 + j] = ls[cc*65 + j];     // coalesced write
  }
  if (bi != 0) return;

  // ---- GRU cell (block 0 only) ----
  for (int r = t; r < 384; r += 256) {
    const int b2 = r / 192, j = r - b2*192;
    const float4* wi4 = (const float4*)(W_ih + (size_t)j*64);
    const float4* wh4 = (const float4*)(W_hh + (size_t)j*64);
    const float4* mu4 = (const float4*)(mu + b2*64);
    const float4* pv4 = (const float4*)(prev + b2*64);
    float sgi = b_ih[j], sgh = b_hh[j];
    #pragma unroll
    for (int k = 0; k < 16; ++k) {
      float4 wv = wi4[k], m4 = mu4[k];
      sgi = fmaf(wv.x, m4.x, sgi); sgi = fmaf(wv.y, m4.y, sgi);
      sgi = fmaf(wv.z, m4.z, sgi); sgi = fmaf(wv.w, m4.w, sgi);
      float4 hv = wh4[k], p4 = pv4[k];
      sgh = fmaf(hv.x, p4.x, sgh); sgh = fmaf(hv.y, p4.y, sgh);
      sgh = fmaf(hv.z, p4.z, sgh); sgh = fmaf(hv.w, p4.w, sgh);
    }
    gi[r] = sgi; gh[r] = sgh;
  }
  __syncthreads();
  if (t < 128) {
    const int b2 = t >> 6, cc = t & 63;
    float ir = gi[b2*192 + cc],       hr = gh[b2*192 + cc];
    float iz = gi[b2*192 + 64 + cc],  hz = gh[b2*192 + 64 + cc];
    float ii = gi[b2*192 + 128 + cc], hn = gh[b2*192 + 128 + cc];
    float rr = 1.0f / (1.0f + __builtin_amdgcn_exp2f(-LOG2E * (ir + hr)));
    float zz = 1.0f / (1.0f + __builtin_amdgcn_exp2f(-LOG2E * (iz + hz)));
    float ng = tanhf(ii + rr * hn);
    outmem[t] = (1.0f - zz) * ng + zz * prev[t];
  }
}

// ---------------------------------------------------------------------------
extern "C" void kernel_launch(void* const* d_in, const int* in_sizes, int n_in,
                              void* d_out, int out_size, void* d_ws, size_t ws_size,
                              hipStream_t stream) {
  const float* x    = (const float*)d_in[0];
  const float* prev = (const float*)d_in[1];
  const float* Wq   = (const float*)d_in[2];
  const float* bq   = (const float*)d_in[3];
  const float* Wk   = (const float*)d_in[4];
  const float* bk   = (const float*)d_in[5];
  const float* Wv   = (const float*)d_in[6];
  const float* bv   = (const float*)d_in[7];
  const float* memk = (const float*)d_in[8];
  const float* memv = (const float*)d_in[9];
  const float* Wg   = (const float*)d_in[10];
  const float* bg   = (const float*)d_in[11];
  const float* W_ih = (const float*)d_in[12];
  const float* W_hh = (const float*)d_in[13];
  const float* b_ih = (const float*)d_in[14];
  const float* b_hh = (const float*)d_in[15];

  float* out    = (float*)d_out;                 // (B,C,H,D,W)
  float* outmem = out + (size_t)BTCH*CDIM*NPOS;  // (B,C)

  const size_t SZ = (size_t)BTCH*NPOS*CDIM;      // 1769472
  float* wsf        = (float*)d_ws;
  float* OT         = wsf;                       // attn result (N,C)
  unsigned int* KVp = (unsigned int*)(wsf + SZ); // bf16 K|V packed
  float* QGX        = wsf + 2*SZ;                // 2 floats per (p,c)
  float* pool       = wsf + 4*SZ;                // 128 floats

  qkvg_kernel<<<BTCH*216, 256, 0, stream>>>(x, Wq, bq, Wk, bk, Wv, bv, Wg,
                                            KVp, QGX, pool);
  attn_kernel<<<BTCH*512, 256, 0, stream>>>(OT, KVp, QGX,
                                            bk, bv, memk, memv, Wg, bg, pool);
  outpool_kernel<<<BTCH*216, 256, 0, stream>>>(OT, out, pool, prev,
                                               W_ih, W_hh, b_ih, b_hh, outmem);
}

// Round 11
// 161.222 us; speedup vs baseline: 1.5073x; 1.0276x over previous
//
#include <hip/hip_runtime.h>
#include <math.h>

#define NPOS 13824   // 24*24*24
#define CDIM 64
#define BTCH 2
#define LOG2E 1.4426950408889634f
#define QSCALE (0.125f * LOG2E)

__device__ __forceinline__ unsigned int f2bf1(float f) {   // RNE float->bf16
  unsigned int u = __float_as_uint(f);
  return (u + 0x7FFFu + ((u >> 16) & 1u)) >> 16;
}

// ---------------------------------------------------------------------------
// Kernel 1: projections. Outputs: KVp = bf16 K|V packed (N,C, bias incl.),
// Qs = pre-scaled Q (N,C), GXCN = gate x-half logit in (C,N) layout (written
// transposed straight from registers). Zeroes pool + ticket counter.
// ---------------------------------------------------------------------------
__global__ __launch_bounds__(256) void qkvg_kernel(
    const float* __restrict__ x,
    const float* __restrict__ Wq, const float* __restrict__ bq,
    const float* __restrict__ Wk, const float* __restrict__ bk,
    const float* __restrict__ Wv, const float* __restrict__ bv,
    const float* __restrict__ Wg,
    unsigned int* __restrict__ KVp, float* __restrict__ Qs,
    float* __restrict__ GXCN, float* __restrict__ pool)
{
  __shared__ __align__(16) float wqt[64*68];
  __shared__ __align__(16) float wkt[64*68];
  __shared__ __align__(16) float wvt[64*68];
  __shared__ __align__(16) float wgt[64*68];
  const int t  = threadIdx.x;
  const int bi = blockIdx.x;
  const int b  = bi / 216;
  const int n0 = (bi - b*216) * 64;
  if (bi == 0 && t < 132) pool[t] = 0.0f;   // pool[128] + ticket counter

  #pragma unroll
  for (int k = 0; k < 16; ++k) {
    int idx = t + k*256;                 // 0..4095
    int lo = idx & 63, hi = idx >> 6;
    wqt[lo*68 + hi] = Wq[idx] * QSCALE;  // [c_in][c_out], Q pre-scaled
    wkt[lo*68 + hi] = Wk[idx];
    wvt[lo*68 + hi] = Wv[idx];
    wgt[lo*68 + hi] = Wg[hi*128 + lo];   // first 64 columns of Wg
  }
  __syncthreads();

  const int c0  = (t & 15) * 4;          // 4 output channels
  const int nn0 = (t >> 4) * 4;          // 4 positions
  const float* xbase = x + (size_t)(b*64)*NPOS + n0 + nn0;
  float aq[4][4] = {}; float ak[4][4] = {}; float av[4][4] = {}; float ag[4][4] = {};
  #pragma unroll 4
  for (int cp = 0; cp < 64; ++cp) {
    const float4 xv4 = *(const float4*)(xbase + (size_t)cp*NPOS);
    const float4 q4  = *(const float4*)&wqt[cp*68 + c0];
    const float4 k4  = *(const float4*)&wkt[cp*68 + c0];
    const float4 v4  = *(const float4*)&wvt[cp*68 + c0];
    const float4 g4  = *(const float4*)&wgt[cp*68 + c0];
    const float xa[4] = {xv4.x, xv4.y, xv4.z, xv4.w};
    const float qa[4] = {q4.x, q4.y, q4.z, q4.w};
    const float ka[4] = {k4.x, k4.y, k4.z, k4.w};
    const float va[4] = {v4.x, v4.y, v4.z, v4.w};
    const float ga[4] = {g4.x, g4.y, g4.z, g4.w};
    #pragma unroll
    for (int ci = 0; ci < 4; ++ci)
      #pragma unroll
      for (int ni = 0; ni < 4; ++ni) {
        aq[ci][ni] = fmaf(qa[ci], xa[ni], aq[ci][ni]);
        ak[ci][ni] = fmaf(ka[ci], xa[ni], ak[ci][ni]);
        av[ci][ni] = fmaf(va[ci], xa[ni], av[ci][ni]);
        ag[ci][ni] = fmaf(ga[ci], xa[ni], ag[ci][ni]);
      }
  }
  const float4 bq4 = *(const float4*)&bq[c0];
  const float4 bk4 = *(const float4*)&bk[c0];
  const float4 bv4 = *(const float4*)&bv[c0];
  const float bqa[4] = {bq4.x, bq4.y, bq4.z, bq4.w};
  const float bka[4] = {bk4.x, bk4.y, bk4.z, bk4.w};
  const float bva[4] = {bv4.x, bv4.y, bv4.z, bv4.w};
  #pragma unroll
  for (int ni = 0; ni < 4; ++ni) {
    const int p = b*NPOS + n0 + nn0 + ni;   // (N,C) layout: [p*64 + c]
    float4 o;
    o = make_float4(fmaf(bqa[0],QSCALE,aq[0][ni]), fmaf(bqa[1],QSCALE,aq[1][ni]),
                    fmaf(bqa[2],QSCALE,aq[2][ni]), fmaf(bqa[3],QSCALE,aq[3][ni]));
    *(float4*)&Qs[p*64 + c0] = o;
    uint4 kv;                               // bf16 K (hi) | V (lo), bias incl.
    kv.x = (f2bf1(ak[0][ni]+bka[0]) << 16) | f2bf1(av[0][ni]+bva[0]);
    kv.y = (f2bf1(ak[1][ni]+bka[1]) << 16) | f2bf1(av[1][ni]+bva[1]);
    kv.z = (f2bf1(ak[2][ni]+bka[2]) << 16) | f2bf1(av[2][ni]+bva[2]);
    kv.w = (f2bf1(ak[3][ni]+bka[3]) << 16) | f2bf1(av[3][ni]+bva[3]);
    *(uint4*)&KVp[p*64 + c0] = kv;
  }
  // GX written transposed (C,N) straight from registers: 16 B runs, the
  // block covers full 256 B per channel-tile -> no partial cache lines.
  #pragma unroll
  for (int ci = 0; ci < 4; ++ci)
    *(float4*)&GXCN[(size_t)(b*64 + c0 + ci)*NPOS + n0 + nn0] =
        make_float4(ag[ci][0], ag[ci][1], ag[ci][2], ag[ci][3]);
}

// ---------------------------------------------------------------------------
// Kernel 2: softmax-only attention. XCD-swizzled 3x3x3 tiles; 5x5x5 bf16
// K|V halo in LDS [c][slot] rows (stride 129 -> ds_read2 pairing, conflict-
// free). 2-position ILP. No gate here (moved to a GEMM in kernel 3) -> tiny
// live set, no spill. NOTE: no min-waves launch bound (R9/R10: (256,4)
// pinned VGPR=64 and spilled ~75 MB to scratch). Writes ATT (N,C).
// ---------------------------------------------------------------------------
__global__ __launch_bounds__(256) void attn_kernel(
    float* __restrict__ ATT,
    const float* __restrict__ Qs,
    const unsigned int* __restrict__ KVp,
    const float* __restrict__ bk, const float* __restrict__ bv,
    const float* __restrict__ memk, const float* __restrict__ memv)
{
  __shared__ __align__(16) unsigned int kvbuf[64*129]; // [c][slot0..124]
  const int t = threadIdx.x;
  const int c = t & 63;
  const int w = t >> 6;

  float mk[5], mv[5];
  #pragma unroll
  for (int m = 0; m < 5; ++m) { mk[m] = memk[c*5 + m]; mv[m] = memv[c*5 + m]; }
  const unsigned bias_kv = (f2bf1(bk[c]) << 16) | f2bf1(bv[c]);

  // XCD-aware swizzle: bi&7 = XCD; contiguous 128-tile slab per XCD
  const int bi = (int)(blockIdx.x & 7) * 128 + (int)(blockIdx.x >> 3);
  const int b  = bi >> 9;                 // 512 tiles (8x8x8) per batch
  const int tb = bi & 511;
  const int h0 = (tb >> 6) * 3;
  const int d0 = ((tb >> 3) & 7) * 3;
  const int w0 = (tb & 7) * 3;
  const int bN = b * NPOS;

  // stage 5x5x5 halo into [c][slot] rows; pos wave-uniform, lane = channel
  for (int u = t; u < 8000; u += 256) {
    const int pos = u >> 6;               // wave-uniform
    const int ph = pos / 25, pr = pos - ph*25;
    const int pd = pr / 5,  pw = pr - pd*5;
    const int hh = h0 - 1 + ph, dd = d0 - 1 + pd, ww = w0 - 1 + pw;
    const bool inb = ((unsigned)hh < 24u) && ((unsigned)dd < 24u) && ((unsigned)ww < 24u);
    unsigned kv = bias_kv;
    if (inb) kv = KVp[(size_t)(bN + hh*576 + dd*24 + ww)*64 + c];
    kvbuf[c*129 + pos] = kv;              // stride 129 == 1 mod 32: conflict-free
  }
  __syncthreads();

  // two positions (li, li+4) per iteration; independent chains for ILP
  for (int li = w; li < 27; li += 8) {
    const int liB0 = li + 4;
    const bool hasB = liB0 < 27;          // wave-uniform
    const int liB = hasB ? liB0 : li;

    const int lhA = li / 9,  lrA = li - lhA*9;
    const int ldA = lrA / 3, lwA = lrA - ldA*3;
    const int pA  = bN + (h0+lhA)*576 + (d0+ldA)*24 + (w0+lwA);
    const unsigned int* kvA = &kvbuf[c*129 + lhA*25 + ldA*5 + lwA];
    const int lhB = liB / 9,  lrB = liB - lhB*9;
    const int ldB = lrB / 3,  lwB = lrB - ldB*3;
    const int pB  = bN + (h0+lhB)*576 + (d0+ldB)*24 + (w0+lwB);
    const unsigned int* kvB = &kvbuf[c*129 + lhB*25 + ldB*5 + lwB];

    const float qA = Qs[pA*64 + c];       // pre-scaled by 0.125*log2e
    const float qB = Qs[pB*64 + c];

    // single-pass softmax (no max subtraction; |logit| <= ~2)
    float sA0 = 0.f, sA1 = 0.f, oA0 = 0.f, oA1 = 0.f;
    float sB0 = 0.f, sB1 = 0.f, oB0 = 0.f, oB1 = 0.f;
    #pragma unroll
    for (int m = 0; m < 5; ++m) {
      const float pfA = __builtin_amdgcn_exp2f(qA * mk[m]);
      const float pfB = __builtin_amdgcn_exp2f(qB * mk[m]);
      if (m & 1) { sA1 += pfA; oA1 = fmaf(pfA, mv[m], oA1);
                   sB1 += pfB; oB1 = fmaf(pfB, mv[m], oB1); }
      else       { sA0 += pfA; oA0 = fmaf(pfA, mv[m], oA0);
                   sB0 += pfB; oB0 = fmaf(pfB, mv[m], oB0); }
    }
    #pragma unroll
    for (int i = 0; i < 3; ++i)
      #pragma unroll
      for (int j = 0; j < 3; ++j)
        #pragma unroll
        for (int l = 0; l < 3; ++l) {
          const int s4  = i*9 + j*3 + l;
          const int off = i*25 + j*5 + l;     // immediate 0..62 -> ds_read2
          const unsigned a = kvA[off], bb2 = kvB[off];
          const float kA = __uint_as_float(a & 0xFFFF0000u);
          const float vA = __uint_as_float(a << 16);
          const float kB = __uint_as_float(bb2 & 0xFFFF0000u);
          const float vB = __uint_as_float(bb2 << 16);
          const float pfA = __builtin_amdgcn_exp2f(qA * kA);
          const float pfB = __builtin_amdgcn_exp2f(qB * kB);
          if (s4 & 1) { sA1 += pfA; oA1 = fmaf(pfA, vA, oA1);
                        sB1 += pfB; oB1 = fmaf(pfB, vB, oB1); }
          else        { sA0 += pfA; oA0 = fmaf(pfA, vA, oA0);
                        sB0 += pfB; oB0 = fmaf(pfB, vB, oB0); }
        }
    const float attA = (oA0 + oA1) * __builtin_amdgcn_rcpf(sA0 + sA1);
    const float attB = (oB0 + oB1) * __builtin_amdgcn_rcpf(sB0 + sB1);
    ATT[pA*64 + c] = attA;                // coalesced full-line (N,C) stores
    if (hasB) ATT[pB*64 + c] = attB;
  }
}

// ---------------------------------------------------------------------------
// Kernel 3: gate as register-blocked GEMM (logit = GXCN + Wg2^T . ATT), final
// mix, direct (B,C,N) output (full-line writes), fused pool reduction, and
// GRU in the last block via device-scope ticket.
// ---------------------------------------------------------------------------
__global__ __launch_bounds__(256) void gateout_kernel(
    const float* __restrict__ ATT, const float* __restrict__ GXCN,
    const float* __restrict__ x, const float* __restrict__ Wg,
    const float* __restrict__ bg,
    float* __restrict__ out, float* __restrict__ pool, int* __restrict__ cnt,
    const float* __restrict__ prev,
    const float* __restrict__ W_ih, const float* __restrict__ W_hh,
    const float* __restrict__ b_ih, const float* __restrict__ b_hh,
    float* __restrict__ outmem)
{
  __shared__ __align__(16) float wgt[64*68];   // Wg[:,64:]^T: [cp][c]
  __shared__ __align__(16) float ats[64*68];   // att tile: [cp][nn]
  __shared__ __align__(16) float psum[1024];
  __shared__ __align__(16) float mu[128];
  __shared__ float gi[384];
  __shared__ float gh[384];
  __shared__ int flag;
  const int t  = threadIdx.x;
  const int bi = blockIdx.x;
  const int b  = bi / 216;
  const int n0 = (bi - b*216) * 64;
  const int bN = b * NPOS;
  if (t == 0) flag = 0;

  #pragma unroll
  for (int k = 0; k < 16; ++k) {
    int u = t + k*256;                    // 0..4095
    int cp = u & 63, co = u >> 6;
    wgt[cp*68 + co] = Wg[co*128 + 64 + cp];   // coalesced read, 8-way LDS write
    int pos = u >> 6, cc = u & 63;
    ats[cc*68 + pos] = ATT[(size_t)(bN + n0 + pos)*64 + cc]; // coalesced read
  }
  __syncthreads();

  const int c0  = (t & 15) * 4;           // 4 output channels
  const int nn0 = (t >> 4) * 4;           // 4 positions
  const float4 bg4 = *(const float4*)&bg[c0];
  float g[4][4];
  #pragma unroll
  for (int ci = 0; ci < 4; ++ci) {
    const float4 gx4 = *(const float4*)&GXCN[(size_t)(b*64 + c0 + ci)*NPOS + n0 + nn0];
    const float bgc = (ci == 0) ? bg4.x : (ci == 1) ? bg4.y : (ci == 2) ? bg4.z : bg4.w;
    g[ci][0] = gx4.x + bgc; g[ci][1] = gx4.y + bgc;
    g[ci][2] = gx4.z + bgc; g[ci][3] = gx4.w + bgc;
  }
  #pragma unroll 4
  for (int cp = 0; cp < 64; ++cp) {
    const float4 w4 = *(const float4*)&wgt[cp*68 + c0];
    const float4 a4 = *(const float4*)&ats[cp*68 + nn0];
    const float wa[4] = {w4.x, w4.y, w4.z, w4.w};
    const float aa[4] = {a4.x, a4.y, a4.z, a4.w};
    #pragma unroll
    for (int ci = 0; ci < 4; ++ci)
      #pragma unroll
      for (int ni = 0; ni < 4; ++ni)
        g[ci][ni] = fmaf(wa[ci], aa[ni], g[ci][ni]);
  }
  // epilogue: gate, mix with x, store (B,C,N), per-channel partial sums
  #pragma unroll
  for (int ci = 0; ci < 4; ++ci) {
    const size_t row = (size_t)(b*64 + c0 + ci)*NPOS + n0 + nn0;
    const float4 x4 = *(const float4*)(x + row);
    const float4 a4 = *(const float4*)&ats[(c0 + ci)*68 + nn0];
    const float xa[4] = {x4.x, x4.y, x4.z, x4.w};
    const float aa[4] = {a4.x, a4.y, a4.z, a4.w};
    float fin[4], s = 0.0f;
    #pragma unroll
    for (int ni = 0; ni < 4; ++ni) {
      const float gate = __builtin_amdgcn_rcpf(
          1.0f + __builtin_amdgcn_exp2f(-LOG2E * g[ci][ni]));
      fin[ni] = fmaf(gate, aa[ni] - xa[ni], xa[ni]);
      s += fin[ni];
    }
    *(float4*)(out + row) = make_float4(fin[0], fin[1], fin[2], fin[3]);
    psum[t*4 + ci] = s;
  }
  __syncthreads();
  if (t < 64) {                           // reducer c sums psum[k*64 + c]
    float s = 0.0f;
    #pragma unroll
    for (int k = 0; k < 16; ++k) s += psum[k*64 + t];
    atomicAdd(&pool[b*64 + t], s);
  }
  if (t == 0) {
    __threadfence();
    if (atomicAdd(cnt, 1) == (int)gridDim.x - 1) flag = 1;
  }
  __syncthreads();

  // ---- last block: GRU cell on pooled mean ----
  if (flag) {
    if (t < 128)
      mu[t] = __hip_atomic_load(&pool[t], __ATOMIC_RELAXED,
                                __HIP_MEMORY_SCOPE_AGENT) * (1.0f / (float)NPOS);
    __syncthreads();
    for (int r = t; r < 384; r += 256) {
      const int b2 = r / 192, j = r - b2*192;
      const float4* wi4 = (const float4*)(W_ih + (size_t)j*64);
      const float4* wh4 = (const float4*)(W_hh + (size_t)j*64);
      const float4* mu4 = (const float4*)(mu + b2*64);
      const float4* pv4 = (const float4*)(prev + b2*64);
      float sgi = b_ih[j], sgh = b_hh[j];
      #pragma unroll
      for (int k = 0; k < 16; ++k) {
        float4 wv = wi4[k], m4 = mu4[k];
        sgi = fmaf(wv.x, m4.x, sgi); sgi = fmaf(wv.y, m4.y, sgi);
        sgi = fmaf(wv.z, m4.z, sgi); sgi = fmaf(wv.w, m4.w, sgi);
        float4 hv = wh4[k], p4 = pv4[k];
        sgh = fmaf(hv.x, p4.x, sgh); sgh = fmaf(hv.y, p4.y, sgh);
        sgh = fmaf(hv.z, p4.z, sgh); sgh = fmaf(hv.w, p4.w, sgh);
      }
      gi[r] = sgi; gh[r] = sgh;
    }
    __syncthreads();
    if (t < 128) {
      const int b2 = t >> 6, cc = t & 63;
      float ir = gi[b2*192 + cc],       hr = gh[b2*192 + cc];
      float iz = gi[b2*192 + 64 + cc],  hz = gh[b2*192 + 64 + cc];
      float ii = gi[b2*192 + 128 + cc], hn = gh[b2*192 + 128 + cc];
      float rr = 1.0f / (1.0f + __builtin_amdgcn_exp2f(-LOG2E * (ir + hr)));
      float zz = 1.0f / (1.0f + __builtin_amdgcn_exp2f(-LOG2E * (iz + hz)));
      float ng = tanhf(ii + rr * hn);
      outmem[t] = (1.0f - zz) * ng + zz * prev[t];
    }
  }
}

// ---------------------------------------------------------------------------
extern "C" void kernel_launch(void* const* d_in, const int* in_sizes, int n_in,
                              void* d_out, int out_size, void* d_ws, size_t ws_size,
                              hipStream_t stream) {
  const float* x    = (const float*)d_in[0];
  const float* prev = (const float*)d_in[1];
  const float* Wq   = (const float*)d_in[2];
  const float* bq   = (const float*)d_in[3];
  const float* Wk   = (const float*)d_in[4];
  const float* bk   = (const float*)d_in[5];
  const float* Wv   = (const float*)d_in[6];
  const float* bv   = (const float*)d_in[7];
  const float* memk = (const float*)d_in[8];
  const float* memv = (const float*)d_in[9];
  const float* Wg   = (const float*)d_in[10];
  const float* bg   = (const float*)d_in[11];
  const float* W_ih = (const float*)d_in[12];
  const float* W_hh = (const float*)d_in[13];
  const float* b_ih = (const float*)d_in[14];
  const float* b_hh = (const float*)d_in[15];

  float* out    = (float*)d_out;                 // (B,C,H,D,W)
  float* outmem = out + (size_t)BTCH*CDIM*NPOS;  // (B,C)

  const size_t SZ = (size_t)BTCH*NPOS*CDIM;      // 1769472
  float* wsf        = (float*)d_ws;
  float* ATT        = wsf;                       // att result (N,C)
  unsigned int* KVp = (unsigned int*)(wsf + SZ); // bf16 K|V packed (N,C)
  float* Qs         = wsf + 2*SZ;                // pre-scaled Q (N,C)
  float* GXCN       = wsf + 3*SZ;                // gate x-half logits (C,N)
  float* pool       = wsf + 4*SZ;                // 128 floats + ticket
  int*   cnt        = (int*)(pool + 128);

  qkvg_kernel<<<BTCH*216, 256, 0, stream>>>(x, Wq, bq, Wk, bk, Wv, bv, Wg,
                                            KVp, Qs, GXCN, pool);
  attn_kernel<<<BTCH*512, 256, 0, stream>>>(ATT, Qs, KVp, bk, bv, memk, memv);
  gateout_kernel<<<BTCH*216, 256, 0, stream>>>(ATT, GXCN, x, Wg, bg,
                                               out, pool, cnt, prev,
                                               W_ih, W_hh, b_ih, b_hh, outmem);
}